// Round 1
// baseline (224.459 us; speedup 1.0000x reference)
//
#include <hip/hip_runtime.h>
#include <cstddef>

// SNN collapses: alpha = expf(-200) == 0.0f in fp32, so LIF(spiking) == floor(relu(x))
// and LIF(readout) == identity. Per-image feed-forward CNN, 1024 independent images.

// ---------------- K1: conv1 (2->8, k2 s2) + floor(relu) + maxpool2 ----------------
// out: (1024, 8, 32, 32). Each pooled pixel owns a disjoint 2ch x 4x4 input patch.
__global__ __launch_bounds__(256) void k1_conv_pool(
    const float* __restrict__ x,    // (1024,2,128,128)
    const float* __restrict__ w1,   // (8,2,2,2)
    float* __restrict__ out)        // (1024,8,32,32)
{
    int idx = blockIdx.x * 256 + threadIdx.x;    // 1024*32*32 work items
    int n  = idx >> 10;
    int py = (idx >> 5) & 31;
    int px = idx & 31;

    float w[64];
#pragma unroll
    for (int i = 0; i < 64; ++i) w[i] = w1[i];   // uniform -> s_load

    const float* xb = x + (size_t)n * (2 * 128 * 128);
    float p[2][4][4];
#pragma unroll
    for (int c = 0; c < 2; ++c)
#pragma unroll
        for (int r = 0; r < 4; ++r) {
            float4 v = *reinterpret_cast<const float4*>(
                xb + (c * 128 + 4 * py + r) * 128 + 4 * px);
            p[c][r][0] = v.x; p[c][r][1] = v.y; p[c][r][2] = v.z; p[c][r][3] = v.w;
        }

    float res[8];
#pragma unroll
    for (int co = 0; co < 8; ++co) res[co] = 0.f;   // floor(relu) >= 0, so 0 is a valid max identity

#pragma unroll
    for (int oy = 0; oy < 2; ++oy)
#pragma unroll
    for (int ox = 0; ox < 2; ++ox)
#pragma unroll
    for (int co = 0; co < 8; ++co) {
        float a = 0.f;
#pragma unroll
        for (int c = 0; c < 2; ++c)
#pragma unroll
        for (int kh = 0; kh < 2; ++kh)
#pragma unroll
        for (int kw = 0; kw < 2; ++kw)
            a += p[c][2 * oy + kh][2 * ox + kw] * w[((co * 2 + c) * 2 + kh) * 2 + kw];
        res[co] = fmaxf(res[co], floorf(fmaxf(a, 0.f)));
    }

    float* ob = out + (size_t)n * 8192 + py * 32 + px;
#pragma unroll
    for (int co = 0; co < 8; ++co) ob[co * 1024] = res[co];   // coalesced per co
}

// ---------------- K2: conv2 (8->8, 3x3 p1) + floor(relu) + maxpool2 ----------------
// One block per image. Zero-padded LDS tile kills all bounds checks.
__global__ __launch_bounds__(256) void k2_conv_pool(
    const float* __restrict__ in,   // (1024,8,32,32)
    const float* __restrict__ w2,   // (8,8,3,3)
    float* __restrict__ out)        // (1024,8,16,16)
{
    __shared__ float tile[8][34][34];   // ~37 KB, zero-padded border
    int n = blockIdx.x;
    int t = threadIdx.x;

    for (int i = t; i < 8 * 34 * 34; i += 256) (&tile[0][0][0])[i] = 0.f;
    __syncthreads();

    const float4* ib4 = reinterpret_cast<const float4*>(in + (size_t)n * 8192);
    for (int i4 = t; i4 < 2048; i4 += 256) {
        float4 v = ib4[i4];
        int ci = i4 >> 8, y = (i4 >> 3) & 31, x4 = (i4 & 7) << 2;
        tile[ci][y + 1][x4 + 1] = v.x;
        tile[ci][y + 1][x4 + 2] = v.y;
        tile[ci][y + 1][x4 + 3] = v.z;
        tile[ci][y + 1][x4 + 4] = v.w;
    }
    __syncthreads();

    int px = t & 15, py = t >> 4;          // pooled pixel, all 8 out-channels per thread
    float acc[8][2][2];
#pragma unroll
    for (int i = 0; i < 32; ++i) (&acc[0][0][0])[i] = 0.f;

    for (int ci = 0; ci < 8; ++ci) {       // rolled: keeps weight SGPR pressure bounded
        float p[4][4];                     // 4x4 patch reused across 8 co (18 MAC/LDS-read)
#pragma unroll
        for (int r = 0; r < 4; ++r)
#pragma unroll
            for (int j = 0; j < 4; ++j)
                p[r][j] = tile[ci][2 * py + r][2 * px + j];
#pragma unroll
        for (int co = 0; co < 8; ++co) {
            const float* wp = w2 + (co * 8 + ci) * 9;   // uniform index -> s_load
            float wv[9];
#pragma unroll
            for (int i = 0; i < 9; ++i) wv[i] = wp[i];
#pragma unroll
            for (int oy = 0; oy < 2; ++oy)
#pragma unroll
            for (int ox = 0; ox < 2; ++ox) {
                float a = acc[co][oy][ox];
#pragma unroll
                for (int kh = 0; kh < 3; ++kh)
#pragma unroll
                for (int kw = 0; kw < 3; ++kw)
                    a += p[oy + kh][ox + kw] * wv[kh * 3 + kw];
                acc[co][oy][ox] = a;
            }
        }
    }

    float* ob = out + (size_t)n * 2048;
#pragma unroll
    for (int co = 0; co < 8; ++co) {
        float m = 0.f;
#pragma unroll
        for (int oy = 0; oy < 2; ++oy)
#pragma unroll
        for (int ox = 0; ox < 2; ++ox)
            m = fmaxf(m, floorf(fmaxf(acc[co][oy][ox], 0.f)));
        ob[co * 256 + t] = m;              // coalesced per co
    }
}

// -------- K3: conv3 (8->8, 3x3 p1) + floor(relu) + maxpool2 + FC(512->2) ----------
// 4 images per block, 64 lanes per image (one wave). Wave-shuffle FC reduction.
__global__ __launch_bounds__(256) void k3_conv_pool_fc(
    const float* __restrict__ in,   // (1024,8,16,16)
    const float* __restrict__ w3,   // (8,8,3,3)
    const float* __restrict__ wfc,  // (2,512)
    float* __restrict__ out)        // (1024,2)
{
    __shared__ float tile[4][8][18][18];   // ~41.5 KB, zero-padded borders
    int t = threadIdx.x;

    for (int i = t; i < 4 * 8 * 18 * 18; i += 256) (&tile[0][0][0][0])[i] = 0.f;
    __syncthreads();

    const float4* ib4 = reinterpret_cast<const float4*>(in) + (size_t)blockIdx.x * 2048;
    for (int i4 = t; i4 < 2048; i4 += 256) {
        float4 v = ib4[i4];
        int sub = i4 >> 9, rem = i4 & 511;
        int ci = rem >> 6, y = (rem >> 2) & 15, x4 = (rem & 3) << 2;
        tile[sub][ci][y + 1][x4 + 1] = v.x;
        tile[sub][ci][y + 1][x4 + 2] = v.y;
        tile[sub][ci][y + 1][x4 + 3] = v.z;
        tile[sub][ci][y + 1][x4 + 4] = v.w;
    }
    __syncthreads();

    int sub = t >> 6;            // image within block (== wave id)
    int l   = t & 63;            // lane
    int py = l >> 3, px = l & 7; // pooled pixel; all 8 co per thread

    float acc[8][2][2];
#pragma unroll
    for (int i = 0; i < 32; ++i) (&acc[0][0][0])[i] = 0.f;

    for (int ci = 0; ci < 8; ++ci) {
        float p[4][4];
#pragma unroll
        for (int r = 0; r < 4; ++r)
#pragma unroll
            for (int j = 0; j < 4; ++j)
                p[r][j] = tile[sub][ci][2 * py + r][2 * px + j];
#pragma unroll
        for (int co = 0; co < 8; ++co) {
            const float* wp = w3 + (co * 8 + ci) * 9;   // uniform -> s_load
            float wv[9];
#pragma unroll
            for (int i = 0; i < 9; ++i) wv[i] = wp[i];
#pragma unroll
            for (int oy = 0; oy < 2; ++oy)
#pragma unroll
            for (int ox = 0; ox < 2; ++ox) {
                float a = acc[co][oy][ox];
#pragma unroll
                for (int kh = 0; kh < 3; ++kh)
#pragma unroll
                for (int kw = 0; kw < 3; ++kw)
                    a += p[oy + kh][ox + kw] * wv[kh * 3 + kw];
                acc[co][oy][ox] = a;
            }
        }
    }

    // pool + floor + FC partials. Flattened feature index o = co*64 + py*8 + px = co*64 + l.
    float p0 = 0.f, p1 = 0.f;
#pragma unroll
    for (int co = 0; co < 8; ++co) {
        float m = 0.f;
#pragma unroll
        for (int oy = 0; oy < 2; ++oy)
#pragma unroll
        for (int ox = 0; ox < 2; ++ox)
            m = fmaxf(m, floorf(fmaxf(acc[co][oy][ox], 0.f)));
        int o = co * 64 + l;
        p0 += m * wfc[o];          // coalesced: lanes read consecutive wfc
        p1 += m * wfc[512 + o];
    }

    // reduce across the wave (one image per wave)
#pragma unroll
    for (int off = 32; off > 0; off >>= 1) {
        p0 += __shfl_down(p0, off);
        p1 += __shfl_down(p1, off);
    }
    if (l == 0) {
        int n = blockIdx.x * 4 + sub;
        out[n * 2 + 0] = p0;
        out[n * 2 + 1] = p1;
    }
}

extern "C" void kernel_launch(void* const* d_in, const int* in_sizes, int n_in,
                              void* d_out, int out_size, void* d_ws, size_t ws_size,
                              hipStream_t stream) {
    const float* x   = (const float*)d_in[0];
    const float* w1  = (const float*)d_in[1];
    const float* w2  = (const float*)d_in[2];
    const float* w3  = (const float*)d_in[3];
    const float* wfc = (const float*)d_in[4];
    float* outp = (float*)d_out;

    float* h1 = (float*)d_ws;                  // (1024,8,32,32) = 32 MB
    float* h2 = h1 + (size_t)1024 * 8192;      // (1024,8,16,16) = 8 MB

    k1_conv_pool<<<4096, 256, 0, stream>>>(x, w1, h1);
    k2_conv_pool<<<1024, 256, 0, stream>>>(h1, w2, h2);
    k3_conv_pool_fc<<<256, 256, 0, stream>>>(h2, w3, wfc, outp);
}

// Round 2
// 209.765 us; speedup vs baseline: 1.0700x; 1.0700x over previous
//
#include <hip/hip_runtime.h>
#include <cstddef>

// SNN collapse: alpha = expf(-1/0.005) = expf(-200) == 0.0f in fp32, so
// LIF(spiking) == floor(relu(x)) elementwise and LIF(readout) == identity.
// Verified R1: absmax 0.0 vs reference. Whole net is per-image feed-forward:
//   conv1(2->8,k2,s2)+floor(relu)+pool2 -> conv2(3x3,p1)+...+pool2
//   -> conv3(3x3,p1)+...+pool2 -> flatten(512) @ w_fc^T -> identity.
// Fully fused: one block per image, intermediates live in LDS (47.4 KB -> 3 blocks/CU).

__global__ __launch_bounds__(256, 4) void fused_snn(
    const float* __restrict__ x,    // (1024,2,128,128)
    const float* __restrict__ w1,   // (8,2,2,2)
    const float* __restrict__ w2,   // (8,8,3,3)
    const float* __restrict__ w3,   // (8,8,3,3)
    const float* __restrict__ wfc,  // (2,512)
    float* __restrict__ out)        // (1024,2)
{
    __shared__ __align__(16) float t1[8][34][34];  // conv1 pooled out, zero-padded border
    __shared__ __align__(16) float t2[8][18][18];  // conv2 pooled out, zero-padded border
    __shared__ float red[8];

    const int n = blockIdx.x;
    const int t = threadIdx.x;

    // zero-init LDS (borders must be zero; zero everything, ~47 stores/thread)
    for (int i = t; i < 8 * 34 * 34; i += 256) (&t1[0][0][0])[i] = 0.f;
    for (int i = t; i < 8 * 18 * 18; i += 256) (&t2[0][0][0])[i] = 0.f;

    // conv1 weights: uniform indices -> scalar loads
    float wa[64];
#pragma unroll
    for (int i = 0; i < 64; ++i) wa[i] = w1[i];
    __syncthreads();

    // ---------------- stage 1: conv1(k2,s2) + floor(relu) + maxpool2 -> t1 interior
    {
        const float* xb = x + (size_t)n * (2 * 128 * 128);
#pragma unroll 1
        for (int k = 0; k < 4; ++k) {
            int i = (k << 8) + t;          // pooled pixel index 0..1023
            int py = i >> 5, px = i & 31;  // consecutive t -> consecutive px: coalesced
            float p[2][4][4];
#pragma unroll
            for (int c = 0; c < 2; ++c)
#pragma unroll
                for (int r = 0; r < 4; ++r) {
                    float4 v = *reinterpret_cast<const float4*>(
                        xb + (c * 128 + 4 * py + r) * 128 + 4 * px);
                    p[c][r][0] = v.x; p[c][r][1] = v.y; p[c][r][2] = v.z; p[c][r][3] = v.w;
                }
#pragma unroll
            for (int co = 0; co < 8; ++co) {
                float m = 0.f;   // floor(relu) >= 0 -> 0 is valid max identity
#pragma unroll
                for (int oy = 0; oy < 2; ++oy)
#pragma unroll
                for (int ox = 0; ox < 2; ++ox) {
                    float a = 0.f;
#pragma unroll
                    for (int c = 0; c < 2; ++c)
#pragma unroll
                    for (int kh = 0; kh < 2; ++kh)
#pragma unroll
                    for (int kw = 0; kw < 2; ++kw)
                        a += p[c][2 * oy + kh][2 * ox + kw] * wa[((co * 2 + c) * 2 + kh) * 2 + kw];
                    m = fmaxf(m, floorf(fmaxf(a, 0.f)));
                }
                t1[co][py + 1][px + 1] = m;
            }
        }
    }
    __syncthreads();

    // ---------------- stage 2: conv2(3x3,p1) + floor(relu) + maxpool2 -> t2 interior
    {
        const int py = t >> 4, px = t & 15;   // pooled pixel, all 8 co per thread
        float acc[8][2][2];
#pragma unroll
        for (int i = 0; i < 32; ++i) (&acc[0][0][0])[i] = 0.f;

#pragma unroll 1
        for (int ci = 0; ci < 8; ++ci) {
            float p[4][4];                    // 4x4 patch, reused by 8 co
#pragma unroll
            for (int r = 0; r < 4; ++r) {
                // float2 (b64) reads: lanes px=0..15 cover the row contiguously -> no bank conflicts
                const float2* row = reinterpret_cast<const float2*>(&t1[ci][2 * py + r][0]);
                float2 a = row[px], b = row[px + 1];
                p[r][0] = a.x; p[r][1] = a.y; p[r][2] = b.x; p[r][3] = b.y;
            }
#pragma unroll
            for (int co = 0; co < 8; ++co) {
                const float* wp = w2 + (co * 8 + ci) * 9;   // uniform -> s_load
                float wv[9];
#pragma unroll
                for (int i = 0; i < 9; ++i) wv[i] = wp[i];
#pragma unroll
                for (int oy = 0; oy < 2; ++oy)
#pragma unroll
                for (int ox = 0; ox < 2; ++ox) {
                    float a = acc[co][oy][ox];
#pragma unroll
                    for (int kh = 0; kh < 3; ++kh)
#pragma unroll
                    for (int kw = 0; kw < 3; ++kw)
                        a += p[oy + kh][ox + kw] * wv[kh * 3 + kw];
                    acc[co][oy][ox] = a;
                }
            }
        }
#pragma unroll
        for (int co = 0; co < 8; ++co) {
            float m = 0.f;
#pragma unroll
            for (int oy = 0; oy < 2; ++oy)
#pragma unroll
            for (int ox = 0; ox < 2; ++ox)
                m = fmaxf(m, floorf(fmaxf(acc[co][oy][ox], 0.f)));
            t2[co][py + 1][px + 1] = m;
        }
    }
    __syncthreads();

    // ------- stage 3: conv3(3x3,p1) + floor(relu) + maxpool2 + FC(512->2) -------
    {
        // wave w handles co pair {2w, 2w+1}; lane l = pooled pixel (8x8)
        const int co2 = __builtin_amdgcn_readfirstlane(t >> 6);  // wave-uniform -> scalar
        const int l = t & 63;
        const int py = l >> 3, px = l & 7;

        float acc[2][2][2];
#pragma unroll
        for (int i = 0; i < 8; ++i) (&acc[0][0][0])[i] = 0.f;

#pragma unroll 1
        for (int ci = 0; ci < 8; ++ci) {
            float p[4][4];
#pragma unroll
            for (int r = 0; r < 4; ++r) {
                const float2* row = reinterpret_cast<const float2*>(&t2[ci][2 * py + r][0]);
                float2 a = row[px], b = row[px + 1];
                p[r][0] = a.x; p[r][1] = a.y; p[r][2] = b.x; p[r][3] = b.y;
            }
#pragma unroll
            for (int cc = 0; cc < 2; ++cc) {
                const float* wp = w3 + ((2 * co2 + cc) * 8 + ci) * 9;  // scalar (co2 uniform)
                float wv[9];
#pragma unroll
                for (int i = 0; i < 9; ++i) wv[i] = wp[i];
#pragma unroll
                for (int oy = 0; oy < 2; ++oy)
#pragma unroll
                for (int ox = 0; ox < 2; ++ox) {
                    float a = acc[cc][oy][ox];
#pragma unroll
                    for (int kh = 0; kh < 3; ++kh)
#pragma unroll
                    for (int kw = 0; kw < 3; ++kw)
                        a += p[oy + kh][ox + kw] * wv[kh * 3 + kw];
                    acc[cc][oy][ox] = a;
                }
            }
        }

        // pool + floor + FC partials; flattened feature o = co*64 + l
        float p0 = 0.f, p1 = 0.f;
#pragma unroll
        for (int cc = 0; cc < 2; ++cc) {
            float m = 0.f;
#pragma unroll
            for (int oy = 0; oy < 2; ++oy)
#pragma unroll
            for (int ox = 0; ox < 2; ++ox)
                m = fmaxf(m, floorf(fmaxf(acc[cc][oy][ox], 0.f)));
            int o = (2 * co2 + cc) * 64 + l;
            p0 += m * wfc[o];          // lanes consecutive -> coalesced
            p1 += m * wfc[512 + o];
        }

        // reduce across the wave, then across the 4 waves via LDS
#pragma unroll
        for (int off = 32; off > 0; off >>= 1) {
            p0 += __shfl_down(p0, off);
            p1 += __shfl_down(p1, off);
        }
        if (l == 0) { red[co2 * 2 + 0] = p0; red[co2 * 2 + 1] = p1; }
    }
    __syncthreads();

    if (t == 0) {
        out[n * 2 + 0] = red[0] + red[2] + red[4] + red[6];
        out[n * 2 + 1] = red[1] + red[3] + red[5] + red[7];
    }
}

extern "C" void kernel_launch(void* const* d_in, const int* in_sizes, int n_in,
                              void* d_out, int out_size, void* d_ws, size_t ws_size,
                              hipStream_t stream) {
    const float* x   = (const float*)d_in[0];
    const float* w1  = (const float*)d_in[1];
    const float* w2  = (const float*)d_in[2];
    const float* w3  = (const float*)d_in[3];
    const float* wfc = (const float*)d_in[4];
    float* outp = (float*)d_out;

    fused_snn<<<1024, 256, 0, stream>>>(x, w1, w2, w3, wfc, outp);
}